// Round 8
// baseline (2891.975 us; speedup 1.0000x reference)
//
#include <hip/hip_runtime.h>
#include <hip/hip_bf16.h>
#include <math.h>

#define C_   1024
#define P_   2304      // 48*48
#define S4   331776    // 24^4

typedef __attribute__((ext_vector_type(8))) short short8;
typedef __attribute__((ext_vector_type(4))) float f32x4;

__device__ inline unsigned short f2bf(float v) {
  unsigned u = __builtin_bit_cast(unsigned, v);
  u += 0x7fffu + ((u >> 16) & 1u);          // RNE
  return (unsigned short)(u >> 16);
}
__device__ inline float bf2f(unsigned short h) {
  unsigned u = ((unsigned)h) << 16;
  return __builtin_bit_cast(float, u);
}

// async global->LDS DMA, 16B per lane; full-exec waves ONLY (partial-exec
// DMA was the prime suspect in the R7 correctness failure).
__device__ inline void async16(const void* g, void* l) {
  __builtin_amdgcn_global_load_lds(
      (const __attribute__((address_space(1))) unsigned int*)g,
      (__attribute__((address_space(3))) unsigned int*)l, 16, 0, 0);
}

// ---------------- K1: transpose + bf16 hi/lo split + sumsq partials --------
__global__ __launch_bounds__(256) void k_prep(
    const float* __restrict__ fA, const float* __restrict__ fB,
    unsigned short* __restrict__ TAhi, unsigned short* __restrict__ TAlo,
    unsigned short* __restrict__ TBhi, unsigned short* __restrict__ TBlo,
    float* __restrict__ part) {
  __shared__ float ld[64 * 65];
  __shared__ float pslds[512];
  const int c0 = blockIdx.x * 64, p0 = blockIdx.y * 64;
  const int fb = blockIdx.z, f = fb >> 3, b = fb & 7;
  const float* src = (f ? fB : fA) + (size_t)b * C_ * P_;
  unsigned short* Thi = (f ? TBhi : TAhi) + (size_t)b * P_ * C_;
  unsigned short* Tlo = (f ? TBlo : TAlo) + (size_t)b * P_ * C_;
  const int t = threadIdx.x;
#pragma unroll
  for (int e = 0; e < 4; ++e) {
    int cid = t + e * 256;                  // 0..1023
    int r = cid >> 4, ch = cid & 15;
    float4 v = *(const float4*)&src[(size_t)(c0 + r) * P_ + p0 + ch * 4];
    ld[r * 65 + ch * 4 + 0] = v.x;
    ld[r * 65 + ch * 4 + 1] = v.y;
    ld[r * 65 + ch * 4 + 2] = v.z;
    ld[r * 65 + ch * 4 + 3] = v.w;
  }
  __syncthreads();
#pragma unroll
  for (int e = 0; e < 2; ++e) {
    int ocid = t + e * 256;                 // 0..511
    int pl = ocid >> 3, c8 = ocid & 7;
    unsigned short hi[8], lo[8];
    float sq = 0.f;
#pragma unroll
    for (int s = 0; s < 8; ++s) {
      float v = ld[(c8 * 8 + s) * 65 + pl];
      unsigned short h = f2bf(v);
      float rem = v - bf2f(h);
      hi[s] = h; lo[s] = f2bf(rem);
      sq = fmaf(v, v, sq);
    }
    size_t go = (size_t)(p0 + pl) * C_ + c0 + c8 * 8;
    *(uint4*)&Thi[go] = *(uint4*)hi;
    *(uint4*)&Tlo[go] = *(uint4*)lo;
    pslds[ocid] = sq;
  }
  __syncthreads();
  if (t < 64) {
    float s = 0.f;
#pragma unroll
    for (int c8 = 0; c8 < 8; ++c8) s += pslds[t * 8 + c8];
    part[((size_t)fb * 16 + blockIdx.x) * P_ + p0 + t] = s;
  }
}

// ---------------- K2: finalize inverse norms -------------------------------
__global__ void k_invnorm(const float* __restrict__ part, float* __restrict__ inv) {
  int p = blockIdx.x * 256 + threadIdx.x;
  int fb = blockIdx.y;
  float s = 1e-6f;
  for (int ct = 0; ct < 16; ++ct) s += part[((size_t)fb * 16 + ct) * P_ + p];
  inv[(size_t)fb * P_ + p] = 1.0f / sqrtf(s);
}

// ---------------- K3: bf16x3 MFMA correlation + relu/norm/4D-maxpool -------
__global__ __launch_bounds__(256, 3) void k_corr_mfma(
    const unsigned short* __restrict__ TAhi_, const unsigned short* __restrict__ TAlo_,
    const unsigned short* __restrict__ TBhi_, const unsigned short* __restrict__ TBlo_,
    const float* __restrict__ invn, float* __restrict__ pooled) {
  __shared__ __align__(16) char lds_raw[37248];
  unsigned short* stage = (unsigned short*)lds_raw;   // 4 arrays, stride 3840h
  float* epi = (float*)lds_raw;                       // 96x97 f32 overlay

  const int b = blockIdx.y;
  const size_t tb = (size_t)b * P_ * C_;
  const unsigned short* TAhi = TAhi_ + tb;
  const unsigned short* TAlo = TAlo_ + tb;
  const unsigned short* TBhi = TBhi_ + tb;
  const unsigned short* TBlo = TBlo_ + tb;
  float* out = pooled + (size_t)b * S4;

  const int g = blockIdx.x;
  const int xcd = g & 7, idx = g >> 3;                // idx 0..71
  const int ti = (xcd & 3) * 6 + idx % 6;
  const int tj = (xcd >> 2) * 12 + idx / 6;
  const int p0 = ti * 96, q0 = tj * 96;
  const int t = threadIdx.x;
  const int lane = t & 63, w = t >> 6;
  const int wr = w >> 1, wc = w & 1;
  const int m15 = lane & 15, q4 = lane >> 4;
  const int koff = q4 * 8;

  f32x4 acc[3][3];
#pragma unroll
  for (int a = 0; a < 3; ++a)
#pragma unroll
    for (int c = 0; c < 3; ++c) acc[a][c] = (f32x4){0.f, 0.f, 0.f, 0.f};

  const unsigned short* gld[8];
  int ldsb[8];
#pragma unroll
  for (int e = 0; e < 8; ++e) {
    int chunk = (w * 8 + e) * 64 + lane;
    int arr = chunk / 480;
    int rem = chunk - arr * 480;
    int row = rem / 5, kc = rem - row * 5;
    bool dum = (arr >= 4) || (kc == 4);
    if (arr >= 4) { arr = 0; row = 0; }
    const unsigned short* base = (arr == 0) ? TAhi : (arr == 1) ? TAlo
                               : (arr == 2) ? TBhi : TBlo;
    int pb = (arr < 2) ? p0 : q0;
    gld[e] = base + (size_t)(pb + row) * C_ + (dum ? 0 : kc * 8);
    ldsb[e] = (w * 8 + e) * 1024;           // wave-uniform byte offset
  }

  for (int kt = 0; kt < C_; kt += 32) {
    __syncthreads();                        // frag reads of prev iter done
#pragma unroll
    for (int e = 0; e < 8; ++e)
      async16(gld[e] + kt, lds_raw + ldsb[e]);
    asm volatile("s_waitcnt vmcnt(0)" ::: "memory");
    __syncthreads();                        // stage ready

    const unsigned short* Ah = stage;
    const unsigned short* Al = stage + 3840;
    const unsigned short* Bh = stage + 7680;
    const unsigned short* Bl = stage + 11520;
    short8 ah[3], al[3], bh[3], bl[3];
#pragma unroll
    for (int a = 0; a < 3; ++a) {
      int row = wr * 48 + a * 16 + m15;
      ah[a] = *(const short8*)&Ah[row * 40 + koff];
      al[a] = *(const short8*)&Al[row * 40 + koff];
    }
#pragma unroll
    for (int c = 0; c < 3; ++c) {
      int row = wc * 48 + c * 16 + m15;
      bh[c] = *(const short8*)&Bh[row * 40 + koff];
      bl[c] = *(const short8*)&Bl[row * 40 + koff];
    }
#pragma unroll
    for (int a = 0; a < 3; ++a)
#pragma unroll
      for (int c = 0; c < 3; ++c)
        acc[a][c] = __builtin_amdgcn_mfma_f32_16x16x32_bf16(ah[a], bh[c], acc[a][c], 0, 0, 0);
#pragma unroll
    for (int a = 0; a < 3; ++a)
#pragma unroll
      for (int c = 0; c < 3; ++c)
        acc[a][c] = __builtin_amdgcn_mfma_f32_16x16x32_bf16(ah[a], bl[c], acc[a][c], 0, 0, 0);
#pragma unroll
    for (int a = 0; a < 3; ++a)
#pragma unroll
      for (int c = 0; c < 3; ++c)
        acc[a][c] = __builtin_amdgcn_mfma_f32_16x16x32_bf16(al[a], bh[c], acc[a][c], 0, 0, 0);
  }
  __syncthreads();

  const float* invA = invn + (size_t)b * P_;
  const float* invB = invn + (size_t)(8 + b) * P_;
  float ib[3];
#pragma unroll
  for (int c = 0; c < 3; ++c) ib[c] = invB[q0 + wc * 48 + c * 16 + m15];
#pragma unroll
  for (int a = 0; a < 3; ++a) {
#pragma unroll
    for (int reg = 0; reg < 4; ++reg) {
      int pl = wr * 48 + a * 16 + q4 * 4 + reg;
      float ia = invA[p0 + pl];
#pragma unroll
      for (int c = 0; c < 3; ++c) {
        int ql = wc * 48 + c * 16 + m15;
        epi[pl * 97 + ql] = acc[a][c][reg] * ia * ib[c];
      }
    }
  }
  __syncthreads();

  for (int idx2 = t; idx2 < 576; idx2 += 256) {
    int j = idx2 / 24, l = idx2 % 24;
    float m = -1e30f;
#pragma unroll
    for (int dh = 0; dh < 2; ++dh)
#pragma unroll
      for (int dw = 0; dw < 2; ++dw) {
        int row = dh * 48 + 2 * j + dw;
#pragma unroll
        for (int d2 = 0; d2 < 2; ++d2)
#pragma unroll
          for (int dw2 = 0; dw2 < 2; ++dw2)
            m = fmaxf(m, epi[row * 97 + d2 * 48 + 2 * l + dw2]);
      }
    float r = fmaxf(m, 0.f);
    float v = r / sqrtf(r * r + 1e-6f);
    out[(size_t)(ti * 24 + j) * 576 + tj * 24 + l] = v;
  }
}

// ---------------- K4a: row max (over kl, per ij) ---------------------------
__global__ void k_rowmax(const float* __restrict__ x, float* __restrict__ amax) {
  int row = blockIdx.x;                       // b*576 + ij
  const float* r = x + (size_t)row * 576;
  float m = -1e30f;
  for (int e = threadIdx.x; e < 576; e += 64) m = fmaxf(m, r[e]);
  for (int off = 32; off > 0; off >>= 1) m = fmaxf(m, __shfl_down(m, off, 64));
  if (threadIdx.x == 0) amax[row] = m;
}

// ---------------- K4b: col max (over ij, per kl) ---------------------------
__global__ void k_colmax(const float* __restrict__ x, float* __restrict__ bmax) {
  __shared__ float pl[4][64];
  int b = blockIdx.x, klc = blockIdx.y * 64;
  int t = threadIdx.x;
  int kl = klc + (t & 63), seg = t >> 6;
  const float* xb = x + (size_t)b * S4;
  float m = -1e30f;
  for (int ij = seg * 144; ij < (seg + 1) * 144; ++ij)
    m = fmaxf(m, xb[(size_t)ij * 576 + kl]);
  pl[seg][t & 63] = m;
  __syncthreads();
  if (t < 64) {
    float r = fmaxf(fmaxf(pl[0][t], pl[1][t]), fmaxf(pl[2][t], pl[3][t]));
    bmax[b * 576 + klc + t] = r;
  }
}

// ---------------- K5: mutual matching elementwise --------------------------
__global__ void k_mm_apply(const float* __restrict__ x,
                           const float* __restrict__ amax,
                           const float* __restrict__ bmax,
                           float* __restrict__ y) {
  int i = blockIdx.x * 256 + threadIdx.x;     // < 8*S4
  int b = i / S4, r = i % S4;
  int ij = r / 576, kl = r % 576;
  float c = x[i];
  y[i] = c * (c / (amax[b * 576 + ij] + 1e-5f)) * (c / (bmax[b * 576 + kl] + 1e-5f));
}

// ---------------- K6: 4D conv v4 — float4 staging, zero-filled OOB slabs ---
// Block covers (i, j0..j0+1): 12 shared slabs (3di x 4dj'), each a raw
// contiguous 24x24 (k,l) plane. Staging: 12*144 float4 = exactly 9 vec4
// chunks/thread, global->reg (issued pre-barrier, overlaps prev compute)
// -> ds_write_b128. Slabs with OOB (i,j) are written as ZEROS, so i/j SAME-
// padding is data, not control. k/l padding via cndmask to a zero slot.
// Thread owns (k, l0..l0+5) of one j-half: each weight s_load feeds 6 FMAs.
template <int CIN, int COUT>
__global__ __launch_bounds__(192, 4) void k_conv4d(
    const float* __restrict__ x, size_t xbs,
    const float* __restrict__ w, const float* __restrict__ bias,
    float* __restrict__ y, size_t ybs) {
  __shared__ __align__(16) float tile[12 * 576 + 4];   // slabs + zero slot
  const float* xb = x + xbs * blockIdx.y;
  float* yb = y + ybs * blockIdx.y;
  const int i  = blockIdx.x / 12;
  const int j0 = (blockIdx.x % 12) * 2;
  const int t  = threadIdx.x;                 // 0..191
  const int h  = t / 96, tl = t % 96;         // j-half, index in half
  const int kk = tl >> 2, l0 = (tl & 3) * 6;  // output row, l-group of 6
  const int j  = j0 + h;
  const int ZOFF = 12 * 576;

  if (t == 0) tile[ZOFF] = 0.f;               // the zero slot

  // staging map (ci-invariant): chunk e covers vec4 #(t+e*192) of 12*144
  int goff[9], loff[9];
#pragma unroll
  for (int e = 0; e < 9; ++e) {
    int idx = t + e * 192;
    int slab = idx / 144, c4 = idx % 144;
    int dis = slab >> 2, djp = slab & 3;
    int ii = i + dis - 1, jj = j0 + djp - 1;
    bool ok = (ii >= 0 && ii < 24 && jj >= 0 && jj < 24);
    goff[e] = ok ? ((ii * 24 + jj) * 576 + c4 * 4) : -1;
    loff[e] = slab * 576 + c4 * 4;
  }

  bool cok[8];                                // l-window validity
#pragma unroll
  for (int m = 0; m < 8; ++m) {
    int col = l0 - 1 + m;
    cok[m] = (col >= 0 && col < 24);
  }

  float acc[COUT][6];
#pragma unroll
  for (int co = 0; co < COUT; ++co)
#pragma unroll
    for (int o = 0; o < 6; ++o) acc[co][o] = 0.f;

  for (int ci = 0; ci < CIN; ++ci) {
    float4 v[9];
#pragma unroll
    for (int e = 0; e < 9; ++e) {
      if (goff[e] >= 0) v[e] = *(const float4*)&xb[(size_t)ci * S4 + goff[e]];
      else              v[e] = make_float4(0.f, 0.f, 0.f, 0.f);
    }
    __syncthreads();                          // prev compute reads done
#pragma unroll
    for (int e = 0; e < 9; ++e)
      *(float4*)&tile[loff[e]] = v[e];
    __syncthreads();                          // slabs ready

#pragma unroll
    for (int di = 0; di < 3; ++di) {
#pragma unroll
      for (int dja = 0; dja < 3; ++dja) {
        const int sbase = (di * 4 + dja + h) * 576;
#pragma unroll
        for (int dk = 0; dk < 3; ++dk) {
          const int rr = kk + dk - 1;
          const bool gok = (rr >= 0 && rr < 24);
          const int base = sbase + rr * 24 + l0 - 1;
          float c[8];
#pragma unroll
          for (int m = 0; m < 8; ++m) {
            int a = (gok && cok[m]) ? (base + m) : ZOFF;
            c[m] = tile[a];
          }
          const float* wp = w + (size_t)ci * 81 + (di * 3 + dja) * 9 + dk * 3;
#pragma unroll
          for (int co = 0; co < COUT; ++co) {
            const float* wr = wp + (size_t)co * CIN * 81;
            float w0 = wr[0], w1 = wr[1], w2 = wr[2];
#pragma unroll
            for (int o = 0; o < 6; ++o) {
              acc[co][o] = fmaf(w0, c[o],     acc[co][o]);
              acc[co][o] = fmaf(w1, c[o + 1], acc[co][o]);
              acc[co][o] = fmaf(w2, c[o + 2], acc[co][o]);
            }
          }
        }
      }
    }
  }

  const int obase = (i * 24 + j) * 576 + kk * 24 + l0;
#pragma unroll
  for (int co = 0; co < COUT; ++co) {
    float bv = bias[co];
#pragma unroll
    for (int o = 0; o < 6; ++o) {
      float v2 = fmaxf(acc[co][o] + bv, 0.f);
      yb[(size_t)co * S4 + obase + o] = v2;
    }
  }
}

// ---------------------------------------------------------------------------
extern "C" void kernel_launch(void* const* d_in, const int* in_sizes, int n_in,
                              void* d_out, int out_size, void* d_ws, size_t ws_size,
                              hipStream_t stream) {
  const float* fA = (const float*)d_in[0];
  const float* fB = (const float*)d_in[1];
  const float* w1 = (const float*)d_in[2];
  const float* b1 = (const float*)d_in[3];
  const float* w2 = (const float*)d_in[4];
  const float* b2 = (const float*)d_in[5];
  const float* w3 = (const float*)d_in[6];
  const float* b3 = (const float*)d_in[7];
  float* out = (float*)d_out;

  float* ws = (float*)d_ws;
  size_t off = 0;
  auto alloc = [&](size_t n) {
    float* p = ws + off;
    off += (n + 63) & ~(size_t)63;
    return p;
  };
  float* pooled = alloc((size_t)8 * S4);          // 10.6 MB
  float* C3     = alloc((size_t)8 * S4);          // 10.6 MB
  float* part   = alloc((size_t)16 * 16 * P_);    // 2.4 MB
  float* invn   = alloc((size_t)16 * P_);
  float* amax1  = alloc(8 * 576);
  float* bmax1  = alloc(8 * 576);
  float* amax2  = alloc(8 * 576);
  float* bmax2  = alloc(8 * 576);
  float* X = alloc((size_t)20 * S4 * 8);          // C1+C2 overlay T arrays
  float* C1 = X;
  float* C2 = X + (size_t)10 * S4 * 8;
  unsigned short* TAhi = (unsigned short*)X;      // each 8*P_*C_ ushorts
  unsigned short* TAlo = TAhi + (size_t)8 * P_ * C_;
  unsigned short* TBhi = TAlo + (size_t)8 * P_ * C_;
  unsigned short* TBlo = TBhi + (size_t)8 * P_ * C_;
  (void)in_sizes; (void)n_in; (void)out_size; (void)ws_size;

  // 1+2) transpose/split + norms + MFMA correlation — all batches per dispatch
  k_prep<<<dim3(16, 36, 16), 256, 0, stream>>>(fA, fB, TAhi, TAlo, TBhi, TBlo, part);
  k_invnorm<<<dim3(9, 16), 256, 0, stream>>>(part, invn);
  k_corr_mfma<<<dim3(576, 8), 256, 0, stream>>>(TAhi, TAlo, TBhi, TBlo, invn, pooled);

  // 3) mutual matching #1 (in place)
  k_rowmax<<<dim3(8 * 576), 64, 0, stream>>>(pooled, amax1);
  k_colmax<<<dim3(8, 9), 256, 0, stream>>>(pooled, bmax1);
  k_mm_apply<<<dim3(10368), 256, 0, stream>>>(pooled, amax1, bmax1, pooled);

  // 4) neighbourhood consensus: 3x conv4d + relu, all batches per dispatch
  k_conv4d<1, 10><<<dim3(288, 8), 192, 0, stream>>>(
      pooled, (size_t)S4, w1, b1, C1, (size_t)10 * S4);
  k_conv4d<10, 10><<<dim3(288, 8), 192, 0, stream>>>(
      C1, (size_t)10 * S4, w2, b2, C2, (size_t)10 * S4);
  k_conv4d<10, 1><<<dim3(288, 8), 192, 0, stream>>>(
      C2, (size_t)10 * S4, w3, b3, C3, (size_t)S4);

  // 5) mutual matching #2 -> final output
  k_rowmax<<<dim3(8 * 576), 64, 0, stream>>>(C3, amax2);
  k_colmax<<<dim3(8, 9), 256, 0, stream>>>(C3, bmax2);
  k_mm_apply<<<dim3(10368), 256, 0, stream>>>(C3, amax2, bmax2, out);
}